// Round 3
// baseline (4126.987 us; speedup 1.0000x reference)
//
#include <hip/hip_runtime.h>
#include <hip/hip_bf16.h>

// Problem dims
constexpr int NB = 32, NS = 512, NE = 256, NC = 128, NHD = 256, NG = 1024, NT = 16, NH = 512;

typedef short bf16x8 __attribute__((ext_vector_type(8)));
typedef float f32x4 __attribute__((ext_vector_type(4)));

// ---------------- helpers ----------------
__device__ __forceinline__ unsigned short f2bf(float f) {
    unsigned u = __float_as_uint(f);
    u += 0x7fffu + ((u >> 16) & 1u);
    return (unsigned short)(u >> 16);
}
__device__ __forceinline__ float bf2f(unsigned short s) {
    return __uint_as_float(((unsigned)s) << 16);
}
__device__ __forceinline__ float sigm(float x) { return 1.f / (1.f + __expf(-x)); }
__device__ __forceinline__ float tanh_fast(float x) {
    float xc = fminf(fmaxf(x, -15.f), 15.f);
    float t = __expf(2.f * xc);
    return (t - 1.f) / (t + 1.f);
}

// ---------------- prep: weight transposes ----------------
// wT[e3][c] = conv_w[c][e3]   (e3 = e*3+k, 768x128)
__global__ void k_prep_convw(const float* __restrict__ w, float* __restrict__ wT) {
    int i = blockIdx.x * 256 + threadIdx.x;
    if (i >= 768 * 128) return;
    int e3 = i >> 7, c = i & 127;
    wT[i] = w[c * 768 + e3];
}

// MFMA B-fragment layout for whh (bf16):
// idx bits: e:3 | lane:6 | g:2 | kt:3 | w:3 | bq:1 | d:1
// j = bq*128 + w*16 + (lane&15); k = kt*32 + (lane>>4)*8 + e
// value = whh_d[(g*256 + j)*256 + k]
__global__ void k_prep_whh_frag(const float* __restrict__ whh_f, const float* __restrict__ whh_b,
                                unsigned short* __restrict__ whhF) {
    int i = blockIdx.x * 256 + threadIdx.x;
    if (i >= (1 << 19)) return;
    int e = i & 7;
    int lane = (i >> 3) & 63;
    int g = (i >> 9) & 3;
    int kt = (i >> 11) & 7;
    int w = (i >> 14) & 7;
    int bq = (i >> 17) & 1;
    int d = (i >> 18) & 1;
    const float* src = d ? whh_b : whh_f;
    int j = bq * 128 + w * 16 + (lane & 15);
    int k = kt * 32 + (lane >> 4) * 8 + e;
    whhF[i] = f2bf(src[(g * 256 + j) * 256 + k]);
}

// wihT[d][(e*256+j)*4+g] = wih_d[(g*256+j)*128+e]  (f32)
__global__ void k_prep_wih(const float* __restrict__ wih_f, const float* __restrict__ wih_b,
                           float* __restrict__ wihT) {
    int d = blockIdx.y;
    const float* src = d ? wih_b : wih_f;
    int i = blockIdx.x * 256 + threadIdx.x;
    if (i >= NC * NG) return;
    int g = i & 3, j = (i >> 2) & 255, e = i >> 10;
    wihT[(size_t)d * NC * NG + i] = src[(g * 256 + j) * 128 + e];
}

// bias2[d][j*4+g] = bih[g*256+j] + bhh[g*256+j]
__global__ void k_prep_bias(const float* __restrict__ bih_f, const float* __restrict__ bhh_f,
                            const float* __restrict__ bih_b, const float* __restrict__ bhh_b,
                            float* __restrict__ bias2) {
    int d = blockIdx.y;
    const float* bi = d ? bih_b : bih_f;
    const float* bh = d ? bhh_b : bhh_f;
    int i = blockIdx.x * 256 + threadIdx.x;
    if (i >= NG) return;
    int g = i & 3, j = i >> 2;
    bias2[(size_t)d * NG + i] = bi[g * 256 + j] + bh[g * 256 + j];
}

__global__ void k_zero(int* __restrict__ flags) {
    if (threadIdx.x < 16) flags[threadIdx.x] = 0;
}

// ---------------- embedding + conv1d(k=3,pad=1) + relu ----------------
__global__ __launch_bounds__(128) void k_conv(const int* __restrict__ x,
                                              const float* __restrict__ table,
                                              const float* __restrict__ wT,
                                              const float* __restrict__ conv_b,
                                              float* __restrict__ feat) {
    int b = blockIdx.y;
    int s0 = blockIdx.x * 8;
    int c = threadIdx.x;
    __shared__ float win[10][NE];
    for (int i = 0; i < 10; ++i) {
        int s = s0 - 1 + i;
        if (s < 0 || s >= NS) {
            for (int e = c; e < NE; e += 128) win[i][e] = 0.f;
        } else {
            int tok = x[b * NS + s];
            const float* row = table + (size_t)tok * NE;
            for (int e = c; e < NE; e += 128) win[i][e] = row[e];
        }
    }
    __syncthreads();
    float acc[8];
    float bc = conv_b[c];
#pragma unroll
    for (int p = 0; p < 8; ++p) acc[p] = bc;
    for (int e = 0; e < NE; ++e) {
        float r[10];
#pragma unroll
        for (int i = 0; i < 10; ++i) r[i] = win[i][e];
#pragma unroll
        for (int k = 0; k < 3; ++k) {
            float wv = wT[(e * 3 + k) * NC + c];
#pragma unroll
            for (int p = 0; p < 8; ++p) acc[p] += wv * r[p + k];
        }
    }
#pragma unroll
    for (int p = 0; p < 8; ++p) {
        feat[((size_t)b * NS + s0 + p) * NC + c] = fmaxf(acc[p], 0.f);
    }
}

// ---------------- input-side gates: xg[d][(s*B+b)*256+j]*4+g  (bf16) ----------------
__global__ __launch_bounds__(256) void k_xgate(const float* __restrict__ feat,
                                               const float* __restrict__ wihT,
                                               const float* __restrict__ bias2,
                                               unsigned short* __restrict__ xg) {
    int d = blockIdx.y;
    int p0 = blockIdx.x * 8;  // pair idx = s*NB + b
    int j = threadIdx.x;
    __shared__ float fv[8][NC];
    for (int i = threadIdx.x; i < 8 * NC; i += 256) {
        int p = i >> 7, e = i & 127;
        int idx = p0 + p;
        int s = idx >> 5, b = idx & 31;
        fv[p][e] = feat[((size_t)b * NS + s) * NC + e];
    }
    __syncthreads();
    const float* W = wihT + (size_t)d * NC * NG;
    float b0 = bias2[(size_t)d * NG + j * 4 + 0];
    float b1 = bias2[(size_t)d * NG + j * 4 + 1];
    float b2 = bias2[(size_t)d * NG + j * 4 + 2];
    float b3 = bias2[(size_t)d * NG + j * 4 + 3];
    float acc[8][4];
#pragma unroll
    for (int p = 0; p < 8; ++p) {
        acc[p][0] = b0; acc[p][1] = b1; acc[p][2] = b2; acc[p][3] = b3;
    }
    for (int e = 0; e < NC; ++e) {
        float4 w4 = *(const float4*)(W + ((size_t)e * 256 + j) * 4);
#pragma unroll
        for (int p = 0; p < 8; ++p) {
            float fe = fv[p][e];
            acc[p][0] += fe * w4.x;
            acc[p][1] += fe * w4.y;
            acc[p][2] += fe * w4.z;
            acc[p][3] += fe * w4.w;
        }
    }
#pragma unroll
    for (int p = 0; p < 8; ++p) {
        ushort4 o;
        o.x = f2bf(acc[p][0]); o.y = f2bf(acc[p][1]);
        o.z = f2bf(acc[p][2]); o.w = f2bf(acc[p][3]);
        unsigned short* dst = xg + (size_t)d * NS * NB * NG + ((size_t)(p0 + p) * 256 + j) * 4;
        *(ushort4*)dst = o;
    }
}

// ---------------- LSTM recurrence via MFMA, W register-resident ----------------
// grid = 4 blocks: (d = bid>>1, bq = bid&1). 512 threads = 8 waves.
// Block owns cells j in [bq*128, bq*128+128) for all 32 batches.
// Wave w owns cells jj = w*16 + (lane&15); all 4 gates of a cell live in one lane.
__global__ __launch_bounds__(512, 2) void k_lstm2(const unsigned short* __restrict__ whhF,
                                                  const unsigned short* __restrict__ xg,
                                                  float* __restrict__ hcat,
                                                  unsigned short* __restrict__ h_ex,
                                                  int* __restrict__ flags) {
    int bid = blockIdx.x;
    int d = bid >> 1, bq = bid & 1;
    int tid = threadIdx.x;
    int w = tid >> 6, l = tid & 63;
    int l15 = l & 15, lq = l >> 4;
    __shared__ alignas(16) unsigned short hbuf[2][32][264];
    for (int i = tid; i < 2 * 32 * 264; i += 512) (&hbuf[0][0][0])[i] = 0;
    // preload W fragments into registers: 32 frags x 4 VGPR = 128 VGPR/thread
    bf16x8 wf[32];
    const unsigned short* wp = whhF + (((size_t)(d * 2 + bq) * 8 + w) << 14) + (size_t)l * 8;
#pragma unroll
    for (int f = 0; f < 32; ++f) wf[f] = *(const bf16x8*)(wp + f * 512);
    int jg = bq * 128 + w * 16 + l15;  // global cell index this lane owns
    const unsigned short* XG = xg + (size_t)d * NS * NB * NG;
    float cst[2][4] = {};
    int me = d * 2 + bq, peer = d * 2 + (bq ^ 1);
    __syncthreads();
    int cur = 0;
    for (int step = 0; step < NS; ++step) {
        int s = d ? (NS - 1 - step) : step;
        // xg loads: per (mt, r): 4 gates of (b = mt*16+lq*4+r, cell jg)
        unsigned long long xq[2][4];
#pragma unroll
        for (int mt = 0; mt < 2; ++mt)
#pragma unroll
            for (int r = 0; r < 4; ++r)
                xq[mt][r] = *(const unsigned long long*)(XG + (size_t)(s * 32 + mt * 16 + lq * 4 + r) * 1024 + jg * 4);
        f32x4 acc[2][4];
#pragma unroll
        for (int mt = 0; mt < 2; ++mt)
#pragma unroll
            for (int g = 0; g < 4; ++g) {
                f32x4 a;
#pragma unroll
                for (int r = 0; r < 4; ++r)
                    a[r] = bf2f((unsigned short)(xq[mt][r] >> (16 * g)));
                acc[mt][g] = a;
            }
        // MFMA: gates[32 x 512] = h[32 x 256] @ Wslice
#pragma unroll
        for (int kt = 0; kt < 8; ++kt) {
            bf16x8 a0 = *(const bf16x8*)&hbuf[cur][l15][kt * 32 + lq * 8];
            bf16x8 a1 = *(const bf16x8*)&hbuf[cur][16 + l15][kt * 32 + lq * 8];
#pragma unroll
            for (int g = 0; g < 4; ++g) {
                acc[0][g] = __builtin_amdgcn_mfma_f32_16x16x32_bf16(a0, wf[kt * 4 + g], acc[0][g], 0, 0, 0);
                acc[1][g] = __builtin_amdgcn_mfma_f32_16x16x32_bf16(a1, wf[kt * 4 + g], acc[1][g], 0, 0, 0);
            }
        }
        // epilogue: 8 cells per lane, c in registers
        int nxt = cur ^ 1;
        int pp = step & 1;
#pragma unroll
        for (int mt = 0; mt < 2; ++mt) {
            unsigned long long hp = 0;
#pragma unroll
            for (int r = 0; r < 4; ++r) {
                float iv = acc[mt][0][r];
                float fv = acc[mt][1][r];
                float gv = acc[mt][2][r];
                float ov = acc[mt][3][r];
                float c = sigm(fv) * cst[mt][r] + sigm(iv) * tanh_fast(gv);
                cst[mt][r] = c;
                float h = sigm(ov) * tanh_fast(c);
                int b = mt * 16 + lq * 4 + r;
                __builtin_nontemporal_store(h, hcat + (size_t)(s * 32 + b) * NH + d * NHD + jg);
                unsigned short hb = f2bf(h);
                hbuf[nxt][b][jg] = hb;
                hp |= (unsigned long long)hb << (16 * r);
            }
            __builtin_nontemporal_store(hp,
                (unsigned long long*)(h_ex + ((size_t)((pp * 2 + d) * 256 + jg) * 32 + mt * 16 + lq * 4)));
        }
        // cross-block h exchange (parity double-buffered, agent-scope fences)
        __builtin_amdgcn_fence(__ATOMIC_RELEASE, "agent");
        __syncthreads();
        if (tid == 0) {
            __hip_atomic_store(&flags[me], step + 1, __ATOMIC_RELAXED, __HIP_MEMORY_SCOPE_AGENT);
            while (__hip_atomic_load(&flags[peer], __ATOMIC_RELAXED, __HIP_MEMORY_SCOPE_AGENT) < step + 1)
                __builtin_amdgcn_s_sleep(1);
        }
        __syncthreads();
        __builtin_amdgcn_fence(__ATOMIC_ACQUIRE, "agent");
        {
            int j = (bq ^ 1) * 128 + (tid >> 2);
            int b0 = (tid & 3) * 8;
            const unsigned long long* src =
                (const unsigned long long*)(h_ex + ((size_t)((pp * 2 + d) * 256 + j) * 32 + b0));
            unsigned long long v0 = src[0], v1 = src[1];
#pragma unroll
            for (int u = 0; u < 4; ++u) hbuf[nxt][b0 + u][j] = (unsigned short)(v0 >> (16 * u));
#pragma unroll
            for (int u = 0; u < 4; ++u) hbuf[nxt][b0 + 4 + u][j] = (unsigned short)(v1 >> (16 * u));
        }
        __syncthreads();
        cur = nxt;
    }
}

// ---------------- FC to emissions: em[s][b][t] ----------------
__global__ __launch_bounds__(256) void k_fc(const float* __restrict__ hcat,
                                            const float* __restrict__ fc_w,
                                            const float* __restrict__ fc_b,
                                            float* __restrict__ em) {
    int p0 = blockIdx.x * 16;  // 16 pairs (s*NB+b linear)
    __shared__ float hv[16][NH];
    for (int i = threadIdx.x; i < 16 * NH; i += 256) {
        int p = i >> 9, hh = i & 511;
        hv[p][hh] = hcat[(size_t)(p0 + p) * NH + hh];
    }
    __syncthreads();
    int p = threadIdx.x >> 4, t = threadIdx.x & 15;
    const float* fw = fc_w + t * NH;
    float acc = fc_b[t];
#pragma unroll 8
    for (int hh = 0; hh < NH; ++hh) acc += hv[p][hh] * fw[hh];
    em[(size_t)(p0 + p) * NT + t] = acc;
}

// ---------------- CRF NLL per batch (emissions staged in LDS) ----------------
__global__ __launch_bounds__(64) void k_crf(const float* __restrict__ em,
                                            const int* __restrict__ tags,
                                            const int* __restrict__ mask,
                                            const float* __restrict__ start_t,
                                            const float* __restrict__ end_t,
                                            const float* __restrict__ trans,
                                            float* __restrict__ res) {
    int b = blockIdx.x;
    int tid = threadIdx.x;
    __shared__ float em_sh[NS * NT];   // 32 KB
    __shared__ float tr[NT * NT];
    __shared__ float alpha[NT];
    __shared__ float sc_sh;
    for (int i = tid; i < NT * NT; i += 64) tr[i] = trans[i];
    for (int i = tid; i < NS * NT; i += 64) {
        int s = i >> 4, t = i & 15;
        em_sh[i] = em[((size_t)s * NB + b) * NT + t];
    }
    __syncthreads();
    float part = 0.f, msum = 0.f;
    for (int s = tid; s < NS; s += 64) msum += (float)mask[b * NS + s];
    for (int s = 1 + tid; s < NS; s += 64) {
        int pv = tags[b * NS + s - 1], cu = tags[b * NS + s];
        float mm = (float)mask[b * NS + s];
        part += (tr[pv * NT + cu] + em_sh[s * NT + cu]) * mm;
    }
#pragma unroll
    for (int o = 32; o > 0; o >>= 1) {
        part += __shfl_down(part, o);
        msum += __shfl_down(msum, o);
    }
    if (tid == 0) {
        int t0 = tags[b * NS];
        int send = (int)msum - 1;
        sc_sh = start_t[t0] + em_sh[t0] + part + end_t[tags[b * NS + send]];
    }
    if (tid < NT) alpha[tid] = start_t[tid] + em_sh[tid];
    __syncthreads();
    for (int s = 1; s < NS; ++s) {
        float nv = 0.f;
        if (tid < NT) {
            float mx = -1e30f;
#pragma unroll
            for (int t = 0; t < NT; ++t) mx = fmaxf(mx, alpha[t] + tr[t * NT + tid]);
            float sum = 0.f;
#pragma unroll
            for (int t = 0; t < NT; ++t) sum += __expf(alpha[t] + tr[t * NT + tid] - mx);
            nv = mx + __logf(sum) + em_sh[s * NT + tid];
            float mm = (float)mask[b * NS + s];
            nv = (mm > 0.f) ? nv : alpha[tid];
        }
        __syncthreads();
        if (tid < NT) alpha[tid] = nv;
        __syncthreads();
    }
    if (tid == 0) {
        float mx = -1e30f;
        for (int t = 0; t < NT; ++t) mx = fmaxf(mx, alpha[t] + end_t[t]);
        float sum = 0.f;
        for (int t = 0; t < NT; ++t) sum += __expf(alpha[t] + end_t[t] - mx);
        res[b] = sc_sh - (mx + __logf(sum));
    }
}

__global__ void k_final(const float* __restrict__ res, float* __restrict__ out) {
    int tid = threadIdx.x;
    float v = (tid < NB) ? res[tid] : 0.f;
#pragma unroll
    for (int o = 32; o > 0; o >>= 1) v += __shfl_down(v, o);
    if (tid == 0) out[0] = -v / NB;
}

// ---------------- workspace layout ----------------
constexpr size_t SZ_FEAT = (size_t)NB * NS * NC * 4;       // 8 MB
constexpr size_t SZ_WT   = (size_t)768 * 128 * 4;          // 384 KB
constexpr size_t SZ_WHHF = (size_t)(1 << 19) * 2;          // 1 MB (bf16 frags)
constexpr size_t SZ_WIHT = (size_t)2 * NC * NG * 4;        // 1 MB
constexpr size_t SZ_BIAS = (size_t)2 * NG * 4;             // 8 KB
constexpr size_t SZ_HEX  = (size_t)2 * 2 * 256 * 32 * 2;   // 64 KB (parity x dir x j x b)
constexpr size_t SZ_FLAG = 256;
constexpr size_t SZ_XG   = (size_t)2 * NS * NB * NG * 2;   // 64 MB (bf16)
constexpr size_t SZ_HCAT = (size_t)NS * NB * NH * 4;       // 32 MB
constexpr size_t SZ_EM   = (size_t)NS * NB * NT * 4;       // 1 MB

constexpr size_t OFF_FEAT = 0;
constexpr size_t OFF_WT   = OFF_FEAT + SZ_FEAT;
constexpr size_t OFF_WHHF = OFF_WT + SZ_WT;
constexpr size_t OFF_WIHT = OFF_WHHF + SZ_WHHF;
constexpr size_t OFF_BIAS = OFF_WIHT + SZ_WIHT;
constexpr size_t OFF_HEX  = OFF_BIAS + SZ_BIAS;
constexpr size_t OFF_FLAG = OFF_HEX + SZ_HEX;
constexpr size_t OFF_XG   = OFF_FLAG + SZ_FLAG;
constexpr size_t OFF_HCAT = OFF_XG + SZ_XG;
constexpr size_t OFF_EM   = OFF_HCAT + SZ_HCAT;
constexpr size_t OFF_RES  = OFF_EM + SZ_EM;

extern "C" void kernel_launch(void* const* d_in, const int* in_sizes, int n_in,
                              void* d_out, int out_size, void* d_ws, size_t ws_size,
                              hipStream_t stream) {
    const int* x        = (const int*)d_in[0];
    const int* mask     = (const int*)d_in[1];
    const int* tags     = (const int*)d_in[2];
    const float* table  = (const float*)d_in[3];
    const float* conv_w = (const float*)d_in[4];
    const float* conv_b = (const float*)d_in[5];
    const float* wih_f  = (const float*)d_in[6];
    const float* whh_f  = (const float*)d_in[7];
    const float* bih_f  = (const float*)d_in[8];
    const float* bhh_f  = (const float*)d_in[9];
    const float* wih_b  = (const float*)d_in[10];
    const float* whh_b  = (const float*)d_in[11];
    const float* bih_b  = (const float*)d_in[12];
    const float* bhh_b  = (const float*)d_in[13];
    const float* fc_w   = (const float*)d_in[14];
    const float* fc_b   = (const float*)d_in[15];
    const float* start_t = (const float*)d_in[16];
    const float* end_t  = (const float*)d_in[17];
    const float* trans  = (const float*)d_in[18];

    char* ws = (char*)d_ws;
    float* feat = (float*)(ws + OFF_FEAT);
    float* wT   = (float*)(ws + OFF_WT);
    unsigned short* whhF = (unsigned short*)(ws + OFF_WHHF);
    float* wihT = (float*)(ws + OFF_WIHT);
    float* bias2 = (float*)(ws + OFF_BIAS);
    unsigned short* h_ex = (unsigned short*)(ws + OFF_HEX);
    int* flags  = (int*)(ws + OFF_FLAG);
    unsigned short* xg = (unsigned short*)(ws + OFF_XG);
    float* hcat = (float*)(ws + OFF_HCAT);
    float* em   = (float*)(ws + OFF_EM);
    float* res  = (float*)(ws + OFF_RES);

    k_prep_convw<<<dim3(384), 256, 0, stream>>>(conv_w, wT);
    k_prep_whh_frag<<<dim3(2048), 256, 0, stream>>>(whh_f, whh_b, whhF);
    k_prep_wih<<<dim3(512, 2), 256, 0, stream>>>(wih_f, wih_b, wihT);
    k_prep_bias<<<dim3(4, 2), 256, 0, stream>>>(bih_f, bhh_f, bih_b, bhh_b, bias2);
    k_zero<<<dim3(1), 64, 0, stream>>>(flags);
    k_conv<<<dim3(NS / 8, NB), 128, 0, stream>>>(x, table, wT, conv_b, feat);
    k_xgate<<<dim3(NS * NB / 8, 2), 256, 0, stream>>>(feat, wihT, bias2, xg);
    k_lstm2<<<dim3(4), 512, 0, stream>>>(whhF, xg, hcat, h_ex, flags);
    k_fc<<<dim3(NS * NB / 16), 256, 0, stream>>>(hcat, fc_w, fc_b, em);
    k_crf<<<dim3(NB), 64, 0, stream>>>(em, tags, mask, start_t, end_t, trans, res);
    k_final<<<dim3(1), 64, 0, stream>>>(res, (float*)d_out);
}

// Round 4
// 3819.342 us; speedup vs baseline: 1.0805x; 1.0805x over previous
//
#include <hip/hip_runtime.h>
#include <hip/hip_bf16.h>

// Problem dims
constexpr int NB = 32, NS = 512, NE = 256, NC = 128, NHD = 256, NG = 1024, NT = 16, NH = 512;

typedef short bf16x8 __attribute__((ext_vector_type(8)));
typedef float f32x4 __attribute__((ext_vector_type(4)));

// ---------------- helpers ----------------
__device__ __forceinline__ unsigned short f2bf(float f) {
    unsigned u = __float_as_uint(f);
    u += 0x7fffu + ((u >> 16) & 1u);
    return (unsigned short)(u >> 16);
}
__device__ __forceinline__ float bf2f(unsigned short s) {
    return __uint_as_float(((unsigned)s) << 16);
}
__device__ __forceinline__ float sigm(float x) { return 1.f / (1.f + __expf(-x)); }
__device__ __forceinline__ float tanh_fast(float x) {
    float xc = fminf(fmaxf(x, -15.f), 15.f);
    float t = __expf(2.f * xc);
    return (t - 1.f) / (t + 1.f);
}

// ---------------- prep: weight transposes ----------------
// wT[e3][c] = conv_w[c][e3]   (e3 = e*3+k, 768x128)
__global__ void k_prep_convw(const float* __restrict__ w, float* __restrict__ wT) {
    int i = blockIdx.x * 256 + threadIdx.x;
    if (i >= 768 * 128) return;
    int e3 = i >> 7, c = i & 127;
    wT[i] = w[c * 768 + e3];
}

// MFMA B-fragment layout for whh (bf16):
// idx bits: e:3 | lane:6 | g:2 | kt:3 | w:3 | bq:1 | d:1
// j = bq*128 + w*16 + (lane&15); k = kt*32 + (lane>>4)*8 + e
// value = whh_d[(g*256 + j)*256 + k]
__global__ void k_prep_whh_frag(const float* __restrict__ whh_f, const float* __restrict__ whh_b,
                                unsigned short* __restrict__ whhF) {
    int i = blockIdx.x * 256 + threadIdx.x;
    if (i >= (1 << 19)) return;
    int e = i & 7;
    int lane = (i >> 3) & 63;
    int g = (i >> 9) & 3;
    int kt = (i >> 11) & 7;
    int w = (i >> 14) & 7;
    int bq = (i >> 17) & 1;
    int d = (i >> 18) & 1;
    const float* src = d ? whh_b : whh_f;
    int j = bq * 128 + w * 16 + (lane & 15);
    int k = kt * 32 + (lane >> 4) * 8 + e;
    whhF[i] = f2bf(src[(g * 256 + j) * 256 + k]);
}

// wihT[d][(e*256+j)*4+g] = wih_d[(g*256+j)*128+e]  (f32)
__global__ void k_prep_wih(const float* __restrict__ wih_f, const float* __restrict__ wih_b,
                           float* __restrict__ wihT) {
    int d = blockIdx.y;
    const float* src = d ? wih_b : wih_f;
    int i = blockIdx.x * 256 + threadIdx.x;
    if (i >= NC * NG) return;
    int g = i & 3, j = (i >> 2) & 255, e = i >> 10;
    wihT[(size_t)d * NC * NG + i] = src[(g * 256 + j) * 128 + e];
}

// bias2[d][j*4+g] = bih[g*256+j] + bhh[g*256+j]
__global__ void k_prep_bias(const float* __restrict__ bih_f, const float* __restrict__ bhh_f,
                            const float* __restrict__ bih_b, const float* __restrict__ bhh_b,
                            float* __restrict__ bias2) {
    int d = blockIdx.y;
    const float* bi = d ? bih_b : bih_f;
    const float* bh = d ? bhh_b : bhh_f;
    int i = blockIdx.x * 256 + threadIdx.x;
    if (i >= NG) return;
    int g = i & 3, j = i >> 2;
    bias2[(size_t)d * NG + i] = bi[g * 256 + j] + bh[g * 256 + j];
}

__global__ void k_zero(int* __restrict__ flags) {
    if (threadIdx.x < 16) flags[threadIdx.x] = 0;
}

// ---------------- embedding + conv1d(k=3,pad=1) + relu ----------------
__global__ __launch_bounds__(128) void k_conv(const int* __restrict__ x,
                                              const float* __restrict__ table,
                                              const float* __restrict__ wT,
                                              const float* __restrict__ conv_b,
                                              float* __restrict__ feat) {
    int b = blockIdx.y;
    int s0 = blockIdx.x * 8;
    int c = threadIdx.x;
    __shared__ float win[10][NE];
    for (int i = 0; i < 10; ++i) {
        int s = s0 - 1 + i;
        if (s < 0 || s >= NS) {
            for (int e = c; e < NE; e += 128) win[i][e] = 0.f;
        } else {
            int tok = x[b * NS + s];
            const float* row = table + (size_t)tok * NE;
            for (int e = c; e < NE; e += 128) win[i][e] = row[e];
        }
    }
    __syncthreads();
    float acc[8];
    float bc = conv_b[c];
#pragma unroll
    for (int p = 0; p < 8; ++p) acc[p] = bc;
    for (int e = 0; e < NE; ++e) {
        float r[10];
#pragma unroll
        for (int i = 0; i < 10; ++i) r[i] = win[i][e];
#pragma unroll
        for (int k = 0; k < 3; ++k) {
            float wv = wT[(e * 3 + k) * NC + c];
#pragma unroll
            for (int p = 0; p < 8; ++p) acc[p] += wv * r[p + k];
        }
    }
#pragma unroll
    for (int p = 0; p < 8; ++p) {
        feat[((size_t)b * NS + s0 + p) * NC + c] = fmaxf(acc[p], 0.f);
    }
}

// ---------------- input-side gates: xg[d][(s*B+b)*256+j]*4+g  (bf16) ----------------
__global__ __launch_bounds__(256) void k_xgate(const float* __restrict__ feat,
                                               const float* __restrict__ wihT,
                                               const float* __restrict__ bias2,
                                               unsigned short* __restrict__ xg) {
    int d = blockIdx.y;
    int p0 = blockIdx.x * 8;  // pair idx = s*NB + b
    int j = threadIdx.x;
    __shared__ float fv[8][NC];
    for (int i = threadIdx.x; i < 8 * NC; i += 256) {
        int p = i >> 7, e = i & 127;
        int idx = p0 + p;
        int s = idx >> 5, b = idx & 31;
        fv[p][e] = feat[((size_t)b * NS + s) * NC + e];
    }
    __syncthreads();
    const float* W = wihT + (size_t)d * NC * NG;
    float b0 = bias2[(size_t)d * NG + j * 4 + 0];
    float b1 = bias2[(size_t)d * NG + j * 4 + 1];
    float b2 = bias2[(size_t)d * NG + j * 4 + 2];
    float b3 = bias2[(size_t)d * NG + j * 4 + 3];
    float acc[8][4];
#pragma unroll
    for (int p = 0; p < 8; ++p) {
        acc[p][0] = b0; acc[p][1] = b1; acc[p][2] = b2; acc[p][3] = b3;
    }
    for (int e = 0; e < NC; ++e) {
        float4 w4 = *(const float4*)(W + ((size_t)e * 256 + j) * 4);
#pragma unroll
        for (int p = 0; p < 8; ++p) {
            float fe = fv[p][e];
            acc[p][0] += fe * w4.x;
            acc[p][1] += fe * w4.y;
            acc[p][2] += fe * w4.z;
            acc[p][3] += fe * w4.w;
        }
    }
#pragma unroll
    for (int p = 0; p < 8; ++p) {
        ushort4 o;
        o.x = f2bf(acc[p][0]); o.y = f2bf(acc[p][1]);
        o.z = f2bf(acc[p][2]); o.w = f2bf(acc[p][3]);
        unsigned short* dst = xg + (size_t)d * NS * NB * NG + ((size_t)(p0 + p) * 256 + j) * 4;
        *(ushort4*)dst = o;
    }
}

// ---------------- LSTM recurrence via MFMA, W register-resident ----------------
// grid = 4 blocks: (d = bid>>1, bq = bid&1). 512 threads = 8 waves.
// __launch_bounds__(512,1): 1 block/CU -> up to 512 VGPR/wave so wf[32] (128 VGPR)
// stays register-resident (round-3 regression: (512,2) capped at 128 -> full spill).
__global__ __launch_bounds__(512, 1) void k_lstm2(const unsigned short* __restrict__ whhF,
                                                  const unsigned short* __restrict__ xg,
                                                  float* __restrict__ hcat,
                                                  unsigned short* __restrict__ h_ex,
                                                  int* __restrict__ flags) {
    int bid = blockIdx.x;
    int d = bid >> 1, bq = bid & 1;
    int tid = threadIdx.x;
    int w = tid >> 6, l = tid & 63;
    int l15 = l & 15, lq = l >> 4;
    __shared__ alignas(16) unsigned short hbuf[2][32][264];
    for (int i = tid; i < 2 * 32 * 264; i += 512) (&hbuf[0][0][0])[i] = 0;
    // preload W fragments into registers: 32 frags x 4 VGPR = 128 VGPR/thread
    bf16x8 wf[32];
    const unsigned short* wp = whhF + (((size_t)(d * 2 + bq) * 8 + w) << 14) + (size_t)l * 8;
#pragma unroll
    for (int f = 0; f < 32; ++f) wf[f] = *(const bf16x8*)(wp + f * 512);
    int jg = bq * 128 + w * 16 + l15;  // global cell index this lane owns
    const unsigned short* XG = xg + (size_t)d * NS * NB * NG;
    float cst[2][4] = {};
    int me = d * 2 + bq, peer = d * 2 + (bq ^ 1);
    __syncthreads();
    int cur = 0;
    // prefetch xg for step 0
    unsigned long long xq[2][4];
    {
        int s0 = d ? (NS - 1) : 0;
#pragma unroll
        for (int mt = 0; mt < 2; ++mt)
#pragma unroll
            for (int r = 0; r < 4; ++r)
                xq[mt][r] = *(const unsigned long long*)(XG + (size_t)(s0 * 32 + mt * 16 + lq * 4 + r) * 1024 + jg * 4);
    }
    for (int step = 0; step < NS; ++step) {
        int s = d ? (NS - 1 - step) : step;
        // consume xq into accumulators
        f32x4 acc[2][4];
#pragma unroll
        for (int mt = 0; mt < 2; ++mt)
#pragma unroll
            for (int g = 0; g < 4; ++g) {
                f32x4 a;
#pragma unroll
                for (int r = 0; r < 4; ++r)
                    a[r] = bf2f((unsigned short)(xq[mt][r] >> (16 * g)));
                acc[mt][g] = a;
            }
        // prefetch next step's xg (hides under MFMA + exchange)
        {
            int stn = (step + 1 < NS) ? step + 1 : step;
            int sn = d ? (NS - 1 - stn) : stn;
#pragma unroll
            for (int mt = 0; mt < 2; ++mt)
#pragma unroll
                for (int r = 0; r < 4; ++r)
                    xq[mt][r] = *(const unsigned long long*)(XG + (size_t)(sn * 32 + mt * 16 + lq * 4 + r) * 1024 + jg * 4);
        }
        // MFMA: gates[32 x 512] = h[32 x 256] @ Wslice
#pragma unroll
        for (int kt = 0; kt < 8; ++kt) {
            bf16x8 a0 = *(const bf16x8*)&hbuf[cur][l15][kt * 32 + lq * 8];
            bf16x8 a1 = *(const bf16x8*)&hbuf[cur][16 + l15][kt * 32 + lq * 8];
#pragma unroll
            for (int g = 0; g < 4; ++g) {
                acc[0][g] = __builtin_amdgcn_mfma_f32_16x16x32_bf16(a0, wf[kt * 4 + g], acc[0][g], 0, 0, 0);
                acc[1][g] = __builtin_amdgcn_mfma_f32_16x16x32_bf16(a1, wf[kt * 4 + g], acc[1][g], 0, 0, 0);
            }
        }
        // epilogue: 8 cells per lane, c in registers
        int nxt = cur ^ 1;
        int pp = step & 1;
#pragma unroll
        for (int mt = 0; mt < 2; ++mt) {
            unsigned long long hp = 0;
#pragma unroll
            for (int r = 0; r < 4; ++r) {
                float iv = acc[mt][0][r];
                float fv = acc[mt][1][r];
                float gv = acc[mt][2][r];
                float ov = acc[mt][3][r];
                float c = sigm(fv) * cst[mt][r] + sigm(iv) * tanh_fast(gv);
                cst[mt][r] = c;
                float h = sigm(ov) * tanh_fast(c);
                int b = mt * 16 + lq * 4 + r;
                __builtin_nontemporal_store(h, hcat + (size_t)(s * 32 + b) * NH + d * NHD + jg);
                unsigned short hb = f2bf(h);
                hbuf[nxt][b][jg] = hb;
                hp |= (unsigned long long)hb << (16 * r);
            }
            *(unsigned long long*)(h_ex + ((size_t)((pp * 2 + d) * 256 + jg) * 32 + mt * 16 + lq * 4)) = hp;
        }
        // cross-block h exchange (parity double-buffered, agent-scope fences)
        __builtin_amdgcn_fence(__ATOMIC_RELEASE, "agent");
        __syncthreads();
        if (tid == 0) {
            __hip_atomic_store(&flags[me], step + 1, __ATOMIC_RELAXED, __HIP_MEMORY_SCOPE_AGENT);
            while (__hip_atomic_load(&flags[peer], __ATOMIC_RELAXED, __HIP_MEMORY_SCOPE_AGENT) < step + 1)
                __builtin_amdgcn_s_sleep(1);
        }
        __syncthreads();
        __builtin_amdgcn_fence(__ATOMIC_ACQUIRE, "agent");
        {
            int j = (bq ^ 1) * 128 + (tid >> 2);
            int b0 = (tid & 3) * 8;
            const unsigned long long* src =
                (const unsigned long long*)(h_ex + ((size_t)((pp * 2 + d) * 256 + j) * 32 + b0));
            unsigned long long v0 = src[0], v1 = src[1];
#pragma unroll
            for (int u = 0; u < 4; ++u) hbuf[nxt][b0 + u][j] = (unsigned short)(v0 >> (16 * u));
#pragma unroll
            for (int u = 0; u < 4; ++u) hbuf[nxt][b0 + 4 + u][j] = (unsigned short)(v1 >> (16 * u));
        }
        __syncthreads();
        cur = nxt;
    }
}

// ---------------- FC to emissions: em[s][b][t] ----------------
__global__ __launch_bounds__(256) void k_fc(const float* __restrict__ hcat,
                                            const float* __restrict__ fc_w,
                                            const float* __restrict__ fc_b,
                                            float* __restrict__ em) {
    int p0 = blockIdx.x * 16;  // 16 pairs (s*NB+b linear)
    __shared__ float hv[16][NH];
    for (int i = threadIdx.x; i < 16 * NH; i += 256) {
        int p = i >> 9, hh = i & 511;
        hv[p][hh] = hcat[(size_t)(p0 + p) * NH + hh];
    }
    __syncthreads();
    int p = threadIdx.x >> 4, t = threadIdx.x & 15;
    const float* fw = fc_w + t * NH;
    float acc = fc_b[t];
#pragma unroll 8
    for (int hh = 0; hh < NH; ++hh) acc += hv[p][hh] * fw[hh];
    em[(size_t)(p0 + p) * NT + t] = acc;
}

// ---------------- CRF NLL per batch (emissions staged in LDS) ----------------
__global__ __launch_bounds__(64) void k_crf(const float* __restrict__ em,
                                            const int* __restrict__ tags,
                                            const int* __restrict__ mask,
                                            const float* __restrict__ start_t,
                                            const float* __restrict__ end_t,
                                            const float* __restrict__ trans,
                                            float* __restrict__ res) {
    int b = blockIdx.x;
    int tid = threadIdx.x;
    __shared__ float em_sh[NS * NT];   // 32 KB
    __shared__ float tr[NT * NT];
    __shared__ float alpha[NT];
    __shared__ float sc_sh;
    for (int i = tid; i < NT * NT; i += 64) tr[i] = trans[i];
    for (int i = tid; i < NS * NT; i += 64) {
        int s = i >> 4, t = i & 15;
        em_sh[i] = em[((size_t)s * NB + b) * NT + t];
    }
    __syncthreads();
    float part = 0.f, msum = 0.f;
    for (int s = tid; s < NS; s += 64) msum += (float)mask[b * NS + s];
    for (int s = 1 + tid; s < NS; s += 64) {
        int pv = tags[b * NS + s - 1], cu = tags[b * NS + s];
        float mm = (float)mask[b * NS + s];
        part += (tr[pv * NT + cu] + em_sh[s * NT + cu]) * mm;
    }
#pragma unroll
    for (int o = 32; o > 0; o >>= 1) {
        part += __shfl_down(part, o);
        msum += __shfl_down(msum, o);
    }
    if (tid == 0) {
        int t0 = tags[b * NS];
        int send = (int)msum - 1;
        sc_sh = start_t[t0] + em_sh[t0] + part + end_t[tags[b * NS + send]];
    }
    if (tid < NT) alpha[tid] = start_t[tid] + em_sh[tid];
    __syncthreads();
    for (int s = 1; s < NS; ++s) {
        float nv = 0.f;
        if (tid < NT) {
            float mx = -1e30f;
#pragma unroll
            for (int t = 0; t < NT; ++t) mx = fmaxf(mx, alpha[t] + tr[t * NT + tid]);
            float sum = 0.f;
#pragma unroll
            for (int t = 0; t < NT; ++t) sum += __expf(alpha[t] + tr[t * NT + tid] - mx);
            nv = mx + __logf(sum) + em_sh[s * NT + tid];
            float mm = (float)mask[b * NS + s];
            nv = (mm > 0.f) ? nv : alpha[tid];
        }
        __syncthreads();
        if (tid < NT) alpha[tid] = nv;
        __syncthreads();
    }
    if (tid == 0) {
        float mx = -1e30f;
        for (int t = 0; t < NT; ++t) mx = fmaxf(mx, alpha[t] + end_t[t]);
        float sum = 0.f;
        for (int t = 0; t < NT; ++t) sum += __expf(alpha[t] + end_t[t] - mx);
        res[b] = sc_sh - (mx + __logf(sum));
    }
}

__global__ void k_final(const float* __restrict__ res, float* __restrict__ out) {
    int tid = threadIdx.x;
    float v = (tid < NB) ? res[tid] : 0.f;
#pragma unroll
    for (int o = 32; o > 0; o >>= 1) v += __shfl_down(v, o);
    if (tid == 0) out[0] = -v / NB;
}

// ---------------- workspace layout ----------------
constexpr size_t SZ_FEAT = (size_t)NB * NS * NC * 4;       // 8 MB
constexpr size_t SZ_WT   = (size_t)768 * 128 * 4;          // 384 KB
constexpr size_t SZ_WHHF = (size_t)(1 << 19) * 2;          // 1 MB (bf16 frags)
constexpr size_t SZ_WIHT = (size_t)2 * NC * NG * 4;        // 1 MB
constexpr size_t SZ_BIAS = (size_t)2 * NG * 4;             // 8 KB
constexpr size_t SZ_HEX  = (size_t)2 * 2 * 256 * 32 * 2;   // 64 KB (parity x dir x j x b)
constexpr size_t SZ_FLAG = 256;
constexpr size_t SZ_XG   = (size_t)2 * NS * NB * NG * 2;   // 64 MB (bf16)
constexpr size_t SZ_HCAT = (size_t)NS * NB * NH * 4;       // 32 MB
constexpr size_t SZ_EM   = (size_t)NS * NB * NT * 4;       // 1 MB

constexpr size_t OFF_FEAT = 0;
constexpr size_t OFF_WT   = OFF_FEAT + SZ_FEAT;
constexpr size_t OFF_WHHF = OFF_WT + SZ_WT;
constexpr size_t OFF_WIHT = OFF_WHHF + SZ_WHHF;
constexpr size_t OFF_BIAS = OFF_WIHT + SZ_WIHT;
constexpr size_t OFF_HEX  = OFF_BIAS + SZ_BIAS;
constexpr size_t OFF_FLAG = OFF_HEX + SZ_HEX;
constexpr size_t OFF_XG   = OFF_FLAG + SZ_FLAG;
constexpr size_t OFF_HCAT = OFF_XG + SZ_XG;
constexpr size_t OFF_EM   = OFF_HCAT + SZ_HCAT;
constexpr size_t OFF_RES  = OFF_EM + SZ_EM;

extern "C" void kernel_launch(void* const* d_in, const int* in_sizes, int n_in,
                              void* d_out, int out_size, void* d_ws, size_t ws_size,
                              hipStream_t stream) {
    const int* x        = (const int*)d_in[0];
    const int* mask     = (const int*)d_in[1];
    const int* tags     = (const int*)d_in[2];
    const float* table  = (const float*)d_in[3];
    const float* conv_w = (const float*)d_in[4];
    const float* conv_b = (const float*)d_in[5];
    const float* wih_f  = (const float*)d_in[6];
    const float* whh_f  = (const float*)d_in[7];
    const float* bih_f  = (const float*)d_in[8];
    const float* bhh_f  = (const float*)d_in[9];
    const float* wih_b  = (const float*)d_in[10];
    const float* whh_b  = (const float*)d_in[11];
    const float* bih_b  = (const float*)d_in[12];
    const float* bhh_b  = (const float*)d_in[13];
    const float* fc_w   = (const float*)d_in[14];
    const float* fc_b   = (const float*)d_in[15];
    const float* start_t = (const float*)d_in[16];
    const float* end_t  = (const float*)d_in[17];
    const float* trans  = (const float*)d_in[18];

    char* ws = (char*)d_ws;
    float* feat = (float*)(ws + OFF_FEAT);
    float* wT   = (float*)(ws + OFF_WT);
    unsigned short* whhF = (unsigned short*)(ws + OFF_WHHF);
    float* wihT = (float*)(ws + OFF_WIHT);
    float* bias2 = (float*)(ws + OFF_BIAS);
    unsigned short* h_ex = (unsigned short*)(ws + OFF_HEX);
    int* flags  = (int*)(ws + OFF_FLAG);
    unsigned short* xg = (unsigned short*)(ws + OFF_XG);
    float* hcat = (float*)(ws + OFF_HCAT);
    float* em   = (float*)(ws + OFF_EM);
    float* res  = (float*)(ws + OFF_RES);

    k_prep_convw<<<dim3(384), 256, 0, stream>>>(conv_w, wT);
    k_prep_whh_frag<<<dim3(2048), 256, 0, stream>>>(whh_f, whh_b, whhF);
    k_prep_wih<<<dim3(512, 2), 256, 0, stream>>>(wih_f, wih_b, wihT);
    k_prep_bias<<<dim3(4, 2), 256, 0, stream>>>(bih_f, bhh_f, bih_b, bhh_b, bias2);
    k_zero<<<dim3(1), 64, 0, stream>>>(flags);
    k_conv<<<dim3(NS / 8, NB), 128, 0, stream>>>(x, table, wT, conv_b, feat);
    k_xgate<<<dim3(NS * NB / 8, 2), 256, 0, stream>>>(feat, wihT, bias2, xg);
    k_lstm2<<<dim3(4), 512, 0, stream>>>(whhF, xg, hcat, h_ex, flags);
    k_fc<<<dim3(NS * NB / 16), 256, 0, stream>>>(hcat, fc_w, fc_b, em);
    k_crf<<<dim3(NB), 64, 0, stream>>>(em, tags, mask, start_t, end_t, trans, res);
    k_final<<<dim3(1), 64, 0, stream>>>(res, (float*)d_out);
}

// Round 5
// 3241.072 us; speedup vs baseline: 1.2733x; 1.1784x over previous
//
#include <hip/hip_runtime.h>
#include <hip/hip_bf16.h>

// Problem dims
constexpr int NB = 32, NS = 512, NE = 256, NC = 128, NHD = 256, NG = 1024, NT = 16, NH = 512;

typedef short bf16x8 __attribute__((ext_vector_type(8)));
typedef float f32x4 __attribute__((ext_vector_type(4)));

// ---------------- helpers ----------------
__device__ __forceinline__ unsigned short f2bf(float f) {
    unsigned u = __float_as_uint(f);
    u += 0x7fffu + ((u >> 16) & 1u);
    return (unsigned short)(u >> 16);
}
__device__ __forceinline__ float bf2f(unsigned short s) {
    return __uint_as_float(((unsigned)s) << 16);
}
__device__ __forceinline__ float sigm(float x) { return 1.f / (1.f + __expf(-x)); }
__device__ __forceinline__ float tanh_fast(float x) {
    float xc = fminf(fmaxf(x, -15.f), 15.f);
    float t = __expf(2.f * xc);
    return (t - 1.f) / (t + 1.f);
}

// L1/L2-bypassing (coherent-point) ops for cross-XCD exchange — no wbl2/inv fences.
__device__ __forceinline__ void store_u64_cc(unsigned long long* p, unsigned long long v) {
    asm volatile("global_store_dwordx2 %0, %1, off sc0 sc1" :: "v"(p), "v"(v) : "memory");
}
__device__ __forceinline__ unsigned long long load_u64_cc(const unsigned long long* p) {
    unsigned long long r;
    asm volatile("global_load_dwordx2 %0, %1, off sc0 sc1\n\ts_waitcnt vmcnt(0)"
                 : "=v"(r) : "v"(p) : "memory");
    return r;
}
__device__ __forceinline__ void store_u32_cc(int* p, int v) {
    asm volatile("global_store_dword %0, %1, off sc0 sc1" :: "v"(p), "v"(v) : "memory");
}
__device__ __forceinline__ int load_u32_cc(const int* p) {
    int r;
    asm volatile("global_load_dword %0, %1, off sc0 sc1\n\ts_waitcnt vmcnt(0)"
                 : "=v"(r) : "v"(p) : "memory");
    return r;
}

// ---------------- prep: weight transposes ----------------
// wT[e3][c] = conv_w[c][e3]   (e3 = e*3+k, 768x128)
__global__ void k_prep_convw(const float* __restrict__ w, float* __restrict__ wT) {
    int i = blockIdx.x * 256 + threadIdx.x;
    if (i >= 768 * 128) return;
    int e3 = i >> 7, c = i & 127;
    wT[i] = w[c * 768 + e3];
}

// MFMA B-fragment layout for whh (bf16):
// idx bits: e:3 | lane:6 | g:2 | kt:3 | w:3 | bq:1 | d:1
// j = bq*128 + w*16 + (lane&15); k = kt*32 + (lane>>4)*8 + e
// value = whh_d[(g*256 + j)*256 + k]
__global__ void k_prep_whh_frag(const float* __restrict__ whh_f, const float* __restrict__ whh_b,
                                unsigned short* __restrict__ whhF) {
    int i = blockIdx.x * 256 + threadIdx.x;
    if (i >= (1 << 19)) return;
    int e = i & 7;
    int lane = (i >> 3) & 63;
    int g = (i >> 9) & 3;
    int kt = (i >> 11) & 7;
    int w = (i >> 14) & 7;
    int bq = (i >> 17) & 1;
    int d = (i >> 18) & 1;
    const float* src = d ? whh_b : whh_f;
    int j = bq * 128 + w * 16 + (lane & 15);
    int k = kt * 32 + (lane >> 4) * 8 + e;
    whhF[i] = f2bf(src[(g * 256 + j) * 256 + k]);
}

// wihT[d][(e*256+j)*4+g] = wih_d[(g*256+j)*128+e]  (f32)
__global__ void k_prep_wih(const float* __restrict__ wih_f, const float* __restrict__ wih_b,
                           float* __restrict__ wihT) {
    int d = blockIdx.y;
    const float* src = d ? wih_b : wih_f;
    int i = blockIdx.x * 256 + threadIdx.x;
    if (i >= NC * NG) return;
    int g = i & 3, j = (i >> 2) & 255, e = i >> 10;
    wihT[(size_t)d * NC * NG + i] = src[(g * 256 + j) * 128 + e];
}

// bias2[d][j*4+g] = bih[g*256+j] + bhh[g*256+j]
__global__ void k_prep_bias(const float* __restrict__ bih_f, const float* __restrict__ bhh_f,
                            const float* __restrict__ bih_b, const float* __restrict__ bhh_b,
                            float* __restrict__ bias2) {
    int d = blockIdx.y;
    const float* bi = d ? bih_b : bih_f;
    const float* bh = d ? bhh_b : bhh_f;
    int i = blockIdx.x * 256 + threadIdx.x;
    if (i >= NG) return;
    int g = i & 3, j = i >> 2;
    bias2[(size_t)d * NG + i] = bi[g * 256 + j] + bh[g * 256 + j];
}

__global__ void k_zero(int* __restrict__ flags) {
    if (threadIdx.x < 64) flags[threadIdx.x] = 0;
}

// ---------------- embedding + conv1d(k=3,pad=1) + relu ----------------
__global__ __launch_bounds__(128) void k_conv(const int* __restrict__ x,
                                              const float* __restrict__ table,
                                              const float* __restrict__ wT,
                                              const float* __restrict__ conv_b,
                                              float* __restrict__ feat) {
    int b = blockIdx.y;
    int s0 = blockIdx.x * 8;
    int c = threadIdx.x;
    __shared__ float win[10][NE];
    for (int i = 0; i < 10; ++i) {
        int s = s0 - 1 + i;
        if (s < 0 || s >= NS) {
            for (int e = c; e < NE; e += 128) win[i][e] = 0.f;
        } else {
            int tok = x[b * NS + s];
            const float* row = table + (size_t)tok * NE;
            for (int e = c; e < NE; e += 128) win[i][e] = row[e];
        }
    }
    __syncthreads();
    float acc[8];
    float bc = conv_b[c];
#pragma unroll
    for (int p = 0; p < 8; ++p) acc[p] = bc;
    for (int e = 0; e < NE; ++e) {
        float r[10];
#pragma unroll
        for (int i = 0; i < 10; ++i) r[i] = win[i][e];
#pragma unroll
        for (int k = 0; k < 3; ++k) {
            float wv = wT[(e * 3 + k) * NC + c];
#pragma unroll
            for (int p = 0; p < 8; ++p) acc[p] += wv * r[p + k];
        }
    }
#pragma unroll
    for (int p = 0; p < 8; ++p) {
        feat[((size_t)b * NS + s0 + p) * NC + c] = fmaxf(acc[p], 0.f);
    }
}

// ---------------- input-side gates: xg[d][(s*B+b)*256+j]*4+g  (bf16) ----------------
__global__ __launch_bounds__(256) void k_xgate(const float* __restrict__ feat,
                                               const float* __restrict__ wihT,
                                               const float* __restrict__ bias2,
                                               unsigned short* __restrict__ xg) {
    int d = blockIdx.y;
    int p0 = blockIdx.x * 8;  // pair idx = s*NB + b
    int j = threadIdx.x;
    __shared__ float fv[8][NC];
    for (int i = threadIdx.x; i < 8 * NC; i += 256) {
        int p = i >> 7, e = i & 127;
        int idx = p0 + p;
        int s = idx >> 5, b = idx & 31;
        fv[p][e] = feat[((size_t)b * NS + s) * NC + e];
    }
    __syncthreads();
    const float* W = wihT + (size_t)d * NC * NG;
    float b0 = bias2[(size_t)d * NG + j * 4 + 0];
    float b1 = bias2[(size_t)d * NG + j * 4 + 1];
    float b2 = bias2[(size_t)d * NG + j * 4 + 2];
    float b3 = bias2[(size_t)d * NG + j * 4 + 3];
    float acc[8][4];
#pragma unroll
    for (int p = 0; p < 8; ++p) {
        acc[p][0] = b0; acc[p][1] = b1; acc[p][2] = b2; acc[p][3] = b3;
    }
    for (int e = 0; e < NC; ++e) {
        float4 w4 = *(const float4*)(W + ((size_t)e * 256 + j) * 4);
#pragma unroll
        for (int p = 0; p < 8; ++p) {
            float fe = fv[p][e];
            acc[p][0] += fe * w4.x;
            acc[p][1] += fe * w4.y;
            acc[p][2] += fe * w4.z;
            acc[p][3] += fe * w4.w;
        }
    }
#pragma unroll
    for (int p = 0; p < 8; ++p) {
        ushort4 o;
        o.x = f2bf(acc[p][0]); o.y = f2bf(acc[p][1]);
        o.z = f2bf(acc[p][2]); o.w = f2bf(acc[p][3]);
        unsigned short* dst = xg + (size_t)d * NS * NB * NG + ((size_t)(p0 + p) * 256 + j) * 4;
        *(ushort4*)dst = o;
    }
}

// ---------------- LSTM recurrence via MFMA, W register-resident ----------------
// grid = 4 blocks: (d = bid>>1, bq = bid&1). 512 threads = 8 waves.
// Cross-block h exchange via sc0sc1 (coherent-point) stores/loads + per-wave flags:
// wave w of block (d,bq) produces cells w*16..w*16+15; peer wave w consumes exactly those.
// No agent fences (no buffer_wbl2 / buffer_inv) — round-4's ~6 us/step sync cost.
__global__ __launch_bounds__(512, 1) void k_lstm2(const unsigned short* __restrict__ whhF,
                                                  const unsigned short* __restrict__ xg,
                                                  float* __restrict__ hcat,
                                                  unsigned long long* __restrict__ h_ex,
                                                  int* __restrict__ flags) {
    int bid = blockIdx.x;
    int d = bid >> 1, bq = bid & 1;
    int tid = threadIdx.x;
    int w = tid >> 6, l = tid & 63;
    int l15 = l & 15, lq = l >> 4;
    __shared__ alignas(16) unsigned short hbuf[2][32][264];
    for (int i = tid; i < 2 * 32 * 264; i += 512) (&hbuf[0][0][0])[i] = 0;
    // preload W fragments into registers: 32 frags x 4 VGPR = 128 regs/thread (VGPR/AGPR)
    bf16x8 wf[32];
    const unsigned short* wp = whhF + (((size_t)(d * 2 + bq) * 8 + w) << 14) + (size_t)l * 8;
#pragma unroll
    for (int f = 0; f < 32; ++f) wf[f] = *(const bf16x8*)(wp + f * 512);
    int jg = bq * 128 + w * 16 + l15;  // global cell index this lane owns
    const unsigned short* XG = xg + (size_t)d * NS * NB * NG;
    float cst[2][4] = {};
    int me = d * 2 + bq, peer = d * 2 + (bq ^ 1);
    __syncthreads();
    int cur = 0;
    // prefetch xg for step 0
    unsigned long long xq[2][4];
    {
        int s0 = d ? (NS - 1) : 0;
#pragma unroll
        for (int mt = 0; mt < 2; ++mt)
#pragma unroll
            for (int r = 0; r < 4; ++r)
                xq[mt][r] = *(const unsigned long long*)(XG + (size_t)(s0 * 32 + mt * 16 + lq * 4 + r) * 1024 + jg * 4);
    }
    for (int step = 0; step < NS; ++step) {
        int s = d ? (NS - 1 - step) : step;
        // consume xq into accumulators
        f32x4 acc[2][4];
#pragma unroll
        for (int mt = 0; mt < 2; ++mt)
#pragma unroll
            for (int g = 0; g < 4; ++g) {
                f32x4 a;
#pragma unroll
                for (int r = 0; r < 4; ++r)
                    a[r] = bf2f((unsigned short)(xq[mt][r] >> (16 * g)));
                acc[mt][g] = a;
            }
        // prefetch next step's xg (hides under MFMA + exchange)
        {
            int stn = (step + 1 < NS) ? step + 1 : step;
            int sn = d ? (NS - 1 - stn) : stn;
#pragma unroll
            for (int mt = 0; mt < 2; ++mt)
#pragma unroll
                for (int r = 0; r < 4; ++r)
                    xq[mt][r] = *(const unsigned long long*)(XG + (size_t)(sn * 32 + mt * 16 + lq * 4 + r) * 1024 + jg * 4);
        }
        // MFMA: gates[32 x 512] = h[32 x 256] @ Wslice
#pragma unroll
        for (int kt = 0; kt < 8; ++kt) {
            bf16x8 a0 = *(const bf16x8*)&hbuf[cur][l15][kt * 32 + lq * 8];
            bf16x8 a1 = *(const bf16x8*)&hbuf[cur][16 + l15][kt * 32 + lq * 8];
#pragma unroll
            for (int g = 0; g < 4; ++g) {
                acc[0][g] = __builtin_amdgcn_mfma_f32_16x16x32_bf16(a0, wf[kt * 4 + g], acc[0][g], 0, 0, 0);
                acc[1][g] = __builtin_amdgcn_mfma_f32_16x16x32_bf16(a1, wf[kt * 4 + g], acc[1][g], 0, 0, 0);
            }
        }
        // epilogue: 8 cells per lane, c in registers
        int nxt = cur ^ 1;
        int pp = step & 1;
        unsigned long long hp[2];
        unsigned short hb[2][4];
        float hf[2][4];
#pragma unroll
        for (int mt = 0; mt < 2; ++mt) {
            hp[mt] = 0ull;
#pragma unroll
            for (int r = 0; r < 4; ++r) {
                float iv = acc[mt][0][r];
                float fv = acc[mt][1][r];
                float gv = acc[mt][2][r];
                float ov = acc[mt][3][r];
                float c = sigm(fv) * cst[mt][r] + sigm(iv) * tanh_fast(gv);
                cst[mt][r] = c;
                float h = sigm(ov) * tanh_fast(c);
                hf[mt][r] = h;
                unsigned short hbv = f2bf(h);
                hb[mt][r] = hbv;
                hp[mt] |= (unsigned long long)hbv << (16 * r);
            }
        }
        // 1) peer payload to coherence point (issued FIRST so the drain below is cheap)
#pragma unroll
        for (int mt = 0; mt < 2; ++mt)
            store_u64_cc(&h_ex[((size_t)((pp * 2 + d) * 256 + jg)) * 8 + mt * 4 + lq], hp[mt]);
        if (step != NS - 1) {
            asm volatile("s_waitcnt vmcnt(0)" ::: "memory");  // h_ex acked at coherence point
            if (l == 0) store_u32_cc(&flags[me * 8 + w], step + 1);
        }
        // 2) hcat output (fire-and-forget, drains during spin) + own-half hbuf
#pragma unroll
        for (int mt = 0; mt < 2; ++mt)
#pragma unroll
            for (int r = 0; r < 4; ++r) {
                int b = mt * 16 + lq * 4 + r;
                __builtin_nontemporal_store(hf[mt][r], hcat + (size_t)(s * 32 + b) * NH + d * NHD + jg);
                hbuf[nxt][b][jg] = hb[mt][r];
            }
        // 3) per-wave spin on peer wave's flag, then pull its 16 cells
        if (step != NS - 1) {
            while (load_u32_cc(&flags[peer * 8 + w]) < step + 1)
                __builtin_amdgcn_s_sleep(2);
            int j = (bq ^ 1) * 128 + (tid >> 2);
            int bq4 = tid & 3;
            unsigned long long v0 = load_u64_cc(&h_ex[((size_t)((pp * 2 + d) * 256 + j)) * 8 + bq4 * 2]);
            unsigned long long v1 = load_u64_cc(&h_ex[((size_t)((pp * 2 + d) * 256 + j)) * 8 + bq4 * 2 + 1]);
#pragma unroll
            for (int u = 0; u < 4; ++u) hbuf[nxt][bq4 * 8 + u][j] = (unsigned short)(v0 >> (16 * u));
#pragma unroll
            for (int u = 0; u < 4; ++u) hbuf[nxt][bq4 * 8 + 4 + u][j] = (unsigned short)(v1 >> (16 * u));
        }
        __syncthreads();
        cur = nxt;
    }
}

// ---------------- FC to emissions: em[s][b][t] ----------------
__global__ __launch_bounds__(256) void k_fc(const float* __restrict__ hcat,
                                            const float* __restrict__ fc_w,
                                            const float* __restrict__ fc_b,
                                            float* __restrict__ em) {
    int p0 = blockIdx.x * 16;  // 16 pairs (s*NB+b linear)
    __shared__ float hv[16][NH];
    for (int i = threadIdx.x; i < 16 * NH; i += 256) {
        int p = i >> 9, hh = i & 511;
        hv[p][hh] = hcat[(size_t)(p0 + p) * NH + hh];
    }
    __syncthreads();
    int p = threadIdx.x >> 4, t = threadIdx.x & 15;
    const float* fw = fc_w + t * NH;
    float acc = fc_b[t];
#pragma unroll 8
    for (int hh = 0; hh < NH; ++hh) acc += hv[p][hh] * fw[hh];
    em[(size_t)(p0 + p) * NT + t] = acc;
}

// ---------------- CRF NLL per batch (emissions staged in LDS) ----------------
__global__ __launch_bounds__(64) void k_crf(const float* __restrict__ em,
                                            const int* __restrict__ tags,
                                            const int* __restrict__ mask,
                                            const float* __restrict__ start_t,
                                            const float* __restrict__ end_t,
                                            const float* __restrict__ trans,
                                            float* __restrict__ res) {
    int b = blockIdx.x;
    int tid = threadIdx.x;
    __shared__ float em_sh[NS * NT];   // 32 KB
    __shared__ float tr[NT * NT];
    __shared__ float alpha[NT];
    __shared__ float sc_sh;
    for (int i = tid; i < NT * NT; i += 64) tr[i] = trans[i];
    for (int i = tid; i < NS * NT; i += 64) {
        int s = i >> 4, t = i & 15;
        em_sh[i] = em[((size_t)s * NB + b) * NT + t];
    }
    __syncthreads();
    float part = 0.f, msum = 0.f;
    for (int s = tid; s < NS; s += 64) msum += (float)mask[b * NS + s];
    for (int s = 1 + tid; s < NS; s += 64) {
        int pv = tags[b * NS + s - 1], cu = tags[b * NS + s];
        float mm = (float)mask[b * NS + s];
        part += (tr[pv * NT + cu] + em_sh[s * NT + cu]) * mm;
    }
#pragma unroll
    for (int o = 32; o > 0; o >>= 1) {
        part += __shfl_down(part, o);
        msum += __shfl_down(msum, o);
    }
    if (tid == 0) {
        int t0 = tags[b * NS];
        int send = (int)msum - 1;
        sc_sh = start_t[t0] + em_sh[t0] + part + end_t[tags[b * NS + send]];
    }
    if (tid < NT) alpha[tid] = start_t[tid] + em_sh[tid];
    __syncthreads();
    for (int s = 1; s < NS; ++s) {
        float nv = 0.f;
        if (tid < NT) {
            float mx = -1e30f;
#pragma unroll
            for (int t = 0; t < NT; ++t) mx = fmaxf(mx, alpha[t] + tr[t * NT + tid]);
            float sum = 0.f;
#pragma unroll
            for (int t = 0; t < NT; ++t) sum += __expf(alpha[t] + tr[t * NT + tid] - mx);
            nv = mx + __logf(sum) + em_sh[s * NT + tid];
            float mm = (float)mask[b * NS + s];
            nv = (mm > 0.f) ? nv : alpha[tid];
        }
        __syncthreads();
        if (tid < NT) alpha[tid] = nv;
        __syncthreads();
    }
    if (tid == 0) {
        float mx = -1e30f;
        for (int t = 0; t < NT; ++t) mx = fmaxf(mx, alpha[t] + end_t[t]);
        float sum = 0.f;
        for (int t = 0; t < NT; ++t) sum += __expf(alpha[t] + end_t[t] - mx);
        res[b] = sc_sh - (mx + __logf(sum));
    }
}

__global__ void k_final(const float* __restrict__ res, float* __restrict__ out) {
    int tid = threadIdx.x;
    float v = (tid < NB) ? res[tid] : 0.f;
#pragma unroll
    for (int o = 32; o > 0; o >>= 1) v += __shfl_down(v, o);
    if (tid == 0) out[0] = -v / NB;
}

// ---------------- workspace layout ----------------
constexpr size_t SZ_FEAT = (size_t)NB * NS * NC * 4;       // 8 MB
constexpr size_t SZ_WT   = (size_t)768 * 128 * 4;          // 384 KB
constexpr size_t SZ_WHHF = (size_t)(1 << 19) * 2;          // 1 MB (bf16 frags)
constexpr size_t SZ_WIHT = (size_t)2 * NC * NG * 4;        // 1 MB
constexpr size_t SZ_BIAS = (size_t)2 * NG * 4;             // 8 KB
constexpr size_t SZ_HEX  = (size_t)2 * 2 * 256 * 32 * 2;   // 64 KB (parity x dir x j x b)
constexpr size_t SZ_FLAG = 256;
constexpr size_t SZ_XG   = (size_t)2 * NS * NB * NG * 2;   // 64 MB (bf16)
constexpr size_t SZ_HCAT = (size_t)NS * NB * NH * 4;       // 32 MB
constexpr size_t SZ_EM   = (size_t)NS * NB * NT * 4;       // 1 MB

constexpr size_t OFF_FEAT = 0;
constexpr size_t OFF_WT   = OFF_FEAT + SZ_FEAT;
constexpr size_t OFF_WHHF = OFF_WT + SZ_WT;
constexpr size_t OFF_WIHT = OFF_WHHF + SZ_WHHF;
constexpr size_t OFF_BIAS = OFF_WIHT + SZ_WIHT;
constexpr size_t OFF_HEX  = OFF_BIAS + SZ_BIAS;
constexpr size_t OFF_FLAG = OFF_HEX + SZ_HEX;
constexpr size_t OFF_XG   = OFF_FLAG + SZ_FLAG;
constexpr size_t OFF_HCAT = OFF_XG + SZ_XG;
constexpr size_t OFF_EM   = OFF_HCAT + SZ_HCAT;
constexpr size_t OFF_RES  = OFF_EM + SZ_EM;

extern "C" void kernel_launch(void* const* d_in, const int* in_sizes, int n_in,
                              void* d_out, int out_size, void* d_ws, size_t ws_size,
                              hipStream_t stream) {
    const int* x        = (const int*)d_in[0];
    const int* mask     = (const int*)d_in[1];
    const int* tags     = (const int*)d_in[2];
    const float* table  = (const float*)d_in[3];
    const float* conv_w = (const float*)d_in[4];
    const float* conv_b = (const float*)d_in[5];
    const float* wih_f  = (const float*)d_in[6];
    const float* whh_f  = (const float*)d_in[7];
    const float* bih_f  = (const float*)d_in[8];
    const float* bhh_f  = (const float*)d_in[9];
    const float* wih_b  = (const float*)d_in[10];
    const float* whh_b  = (const float*)d_in[11];
    const float* bih_b  = (const float*)d_in[12];
    const float* bhh_b  = (const float*)d_in[13];
    const float* fc_w   = (const float*)d_in[14];
    const float* fc_b   = (const float*)d_in[15];
    const float* start_t = (const float*)d_in[16];
    const float* end_t  = (const float*)d_in[17];
    const float* trans  = (const float*)d_in[18];

    char* ws = (char*)d_ws;
    float* feat = (float*)(ws + OFF_FEAT);
    float* wT   = (float*)(ws + OFF_WT);
    unsigned short* whhF = (unsigned short*)(ws + OFF_WHHF);
    float* wihT = (float*)(ws + OFF_WIHT);
    float* bias2 = (float*)(ws + OFF_BIAS);
    unsigned long long* h_ex = (unsigned long long*)(ws + OFF_HEX);
    int* flags  = (int*)(ws + OFF_FLAG);
    unsigned short* xg = (unsigned short*)(ws + OFF_XG);
    float* hcat = (float*)(ws + OFF_HCAT);
    float* em   = (float*)(ws + OFF_EM);
    float* res  = (float*)(ws + OFF_RES);

    k_prep_convw<<<dim3(384), 256, 0, stream>>>(conv_w, wT);
    k_prep_whh_frag<<<dim3(2048), 256, 0, stream>>>(whh_f, whh_b, whhF);
    k_prep_wih<<<dim3(512, 2), 256, 0, stream>>>(wih_f, wih_b, wihT);
    k_prep_bias<<<dim3(4, 2), 256, 0, stream>>>(bih_f, bhh_f, bih_b, bhh_b, bias2);
    k_zero<<<dim3(1), 64, 0, stream>>>(flags);
    k_conv<<<dim3(NS / 8, NB), 128, 0, stream>>>(x, table, wT, conv_b, feat);
    k_xgate<<<dim3(NS * NB / 8, 2), 256, 0, stream>>>(feat, wihT, bias2, xg);
    k_lstm2<<<dim3(4), 512, 0, stream>>>(whhF, xg, hcat, h_ex, flags);
    k_fc<<<dim3(NS * NB / 16), 256, 0, stream>>>(hcat, fc_w, fc_b, em);
    k_crf<<<dim3(NB), 64, 0, stream>>>(em, tags, mask, start_t, end_t, trans, res);
    k_final<<<dim3(1), 64, 0, stream>>>(res, (float*)d_out);
}